// Round 2
// baseline (709.653 us; speedup 1.0000x reference)
//
#include <hip/hip_runtime.h>
#include <hip/hip_bf16.h>

// Problem constants (fixed by setup_inputs)
#define BS   4
#define NQ   6400
#define DIMS 256
#define NH   8
#define NP   4
#define NQUEUE 2
#define GW   80
#define GH   80

typedef __hip_bfloat16 bf16;

__device__ __forceinline__ float b2f(bf16 x) { return __bfloat162float(x); }
__device__ __forceinline__ bf16 f2b(float x) { return __float2bfloat16(x); }

// Flag-predicated input load: inputs are either f32 or bf16 (runtime-detected).
__device__ __forceinline__ float ldin(const void* p, size_t i, int isf32) {
    return isf32 ? ((const float*)p)[i] : b2f(((const bf16*)p)[i]);
}

// ---------------------------------------------------------------------------
// dtype detector: scan first 4096 half-words of query interpreted as bf16.
// bf16-packed N(0,1) data never exceeds exponent 129; f32-packed data's low
// half-words have ~uniform random exponent bits -> values >= 2^33 certain.
// flag=1 -> inputs are f32; flag=0 -> inputs are bf16.
// ---------------------------------------------------------------------------
__global__ void detect_k(const unsigned short* __restrict__ q, int* flag) {
    __shared__ int s;
    if (threadIdx.x == 0) s = 0;
    __syncthreads();
    int bad = 0;
    for (int j = 0; j < 16; ++j) {
        unsigned short v = q[threadIdx.x * 16 + j];
        int e = (v >> 7) & 0xFF;
        if (e > 160) bad = 1;   // |x| >= 2^33: impossible for real bf16 data
    }
    if (bad) atomicOr(&s, 1);
    __syncthreads();
    if (threadIdx.x == 0) *flag = s;
}

// ---------------------------------------------------------------------------
// GEMM, tile 64x64, BK=16, 256 threads, 4x4 micro-tile.
// AMODE 0: A row m -> interleaved value: bq=m/NQ, q=m%NQ,
//          src=(bq&1)?voxbev:query row (bq>>1)*NQ+q   (input dtype via flag)
// AMODE 2: A = plain bf16 pointer (row-major, stride K)
// OUTMODE 1: write bf16 to C
// OUTMODE 2: add ldin(addend) (residual), write C in flag dtype
// B and bias are inputs (flag dtype).
// ---------------------------------------------------------------------------
#define BM 64
#define BN 64
#define BK 16

template <int AMODE, int OUTMODE>
__global__ __launch_bounds__(256) void gemm_k(
    const void* __restrict__ A, const void* __restrict__ B,
    const void* __restrict__ bias, void* __restrict__ C,
    int M, int N, int K,
    const void* __restrict__ query, const void* __restrict__ voxbev,
    const void* __restrict__ addend, const int* __restrict__ flagp)
{
    const int isf = *flagp;
    __shared__ float As[BK][BM];
    __shared__ float Bs[BK][BN];

    const int tid = threadIdx.x;
    const int bm = blockIdx.y * BM;
    const int bn = blockIdx.x * BN;

    const int a_row = tid >> 2;
    const int a_kc  = (tid & 3) * 4;
    const int m     = bm + a_row;
    const int b_row = tid >> 4;
    const int b_col = (tid & 15) * 4;

    const void* asrc = nullptr;
    size_t abase = 0;
    if (AMODE == 0) {
        const int mb = m / NQ, mq = m - (m / NQ) * NQ;
        asrc  = (mb & 1) ? voxbev : query;
        abase = (size_t)((mb >> 1) * NQ + mq) * DIMS;
    }

    const int ty = tid >> 4, tx = tid & 15;
    float acc[4][4] = {};

    for (int k0 = 0; k0 < K; k0 += BK) {
#pragma unroll
        for (int j = 0; j < 4; ++j) {
            const int k = k0 + a_kc + j;
            float av;
            if (AMODE == 0) av = ldin(asrc, abase + k, isf);
            else            av = b2f(((const bf16*)A)[(size_t)m * K + k]);
            As[a_kc + j][a_row] = av;
        }
#pragma unroll
        for (int j = 0; j < 4; ++j)
            Bs[b_row][b_col + j] = ldin(B, (size_t)(k0 + b_row) * N + bn + b_col + j, isf);
        __syncthreads();

#pragma unroll
        for (int kk = 0; kk < BK; ++kk) {
            float a[4], b[4];
#pragma unroll
            for (int i = 0; i < 4; ++i) a[i] = As[kk][ty * 4 + i];
#pragma unroll
            for (int j = 0; j < 4; ++j) b[j] = Bs[kk][tx * 4 + j];
#pragma unroll
            for (int i = 0; i < 4; ++i)
#pragma unroll
                for (int j = 0; j < 4; ++j) acc[i][j] += a[i] * b[j];
        }
        __syncthreads();
    }

#pragma unroll
    for (int i = 0; i < 4; ++i) {
        const int row = bm + ty * 4 + i;
#pragma unroll
        for (int j = 0; j < 4; ++j) {
            const int col = bn + tx * 4 + j;
            float r = acc[i][j] + ldin(bias, col, isf);
            if (OUTMODE == 2) {
                r += ldin(addend, (size_t)row * N + col, isf);
                if (isf) ((float*)C)[(size_t)row * N + col] = r;
                else     ((bf16*)C)[(size_t)row * N + col] = f2b(r);
            } else {
                ((bf16*)C)[(size_t)row * N + col] = f2b(r);
            }
        }
    }
}

// ---------------------------------------------------------------------------
// Fused: off_attn = qcat @ [Woff | Wattn] + bias, then softmax over 4 points
// and sampling-coord computation, writing samp[bq][q][h][p] = {x, y, w, 0}.
// Tile 64 rows x 192 cols, BK=16, 256 threads, 4x12 micro-tile.
// qcat row m (b=m/NQ, q=m%NQ): k<256 -> value row b (interleaved), else query.
// ---------------------------------------------------------------------------
#define OBM 64
#define OBN 192
#define OBK 16

__global__ __launch_bounds__(256) void offattn_k(
    const void* __restrict__ query, const void* __restrict__ voxbev,
    const void* __restrict__ refpts,
    const void* __restrict__ Woff, const void* __restrict__ boff,
    const void* __restrict__ Wattn, const void* __restrict__ battn,
    const int* __restrict__ flagp, float4* __restrict__ samp)
{
    const int isf = *flagp;
    __shared__ union U {
        struct { float As[OBK][OBM]; float Bs[OBK][OBN]; } s;
        float res[OBM][OBN + 1];   // 64 x 193 floats = 49.4 KB
    } u;

    const int tid = threadIdx.x;
    const int bm = blockIdx.x * OBM;

    const int a_row = tid >> 2;
    const int a_kc  = (tid & 3) * 4;
    const int m     = bm + a_row;
    const int mb = m / NQ, mq = m - (m / NQ) * NQ;
    const void* rowlo = (mb & 1) ? voxbev : query;      // value[b] interleaved
    const size_t baselo = (size_t)((mb >> 1) * NQ + mq) * DIMS;
    const size_t basehi = (size_t)(mb * NQ + mq) * DIMS; // query[b][q]

    const int b_row = tid >> 4;        // 0..15
    const int b_colc = (tid & 15) * 12;

    const int ty = tid >> 4, tx = tid & 15;
    float acc[4][12] = {};

    for (int k0 = 0; k0 < 2 * DIMS; k0 += OBK) {
#pragma unroll
        for (int j = 0; j < 4; ++j) {
            const int k = k0 + a_kc + j;
            float av = (k < DIMS) ? ldin(rowlo, baselo + k, isf)
                                  : ldin(query, basehi + (k - DIMS), isf);
            u.s.As[a_kc + j][a_row] = av;
        }
#pragma unroll
        for (int j = 0; j < 12; ++j) {
            const int col = b_colc + j;
            float bv;
            if (col < 128) bv = ldin(Woff,  (size_t)(k0 + b_row) * 128 + col, isf);
            else           bv = ldin(Wattn, (size_t)(k0 + b_row) * 64 + (col - 128), isf);
            u.s.Bs[b_row][col] = bv;
        }
        __syncthreads();

#pragma unroll
        for (int kk = 0; kk < OBK; ++kk) {
            float a[4], b[12];
#pragma unroll
            for (int i = 0; i < 4; ++i) a[i] = u.s.As[kk][ty * 4 + i];
#pragma unroll
            for (int j = 0; j < 12; ++j) b[j] = u.s.Bs[kk][tx * 12 + j];
#pragma unroll
            for (int i = 0; i < 4; ++i)
#pragma unroll
                for (int j = 0; j < 12; ++j) acc[i][j] += a[i] * b[j];
        }
        __syncthreads();
    }

    // bias-add and park results in LDS (As/Bs are dead)
#pragma unroll
    for (int i = 0; i < 4; ++i)
#pragma unroll
        for (int j = 0; j < 12; ++j) {
            const int col = tx * 12 + j;
            float bias = (col < 128) ? ldin(boff, col, isf)
                                     : ldin(battn, col - 128, isf);
            u.res[ty * 4 + i][col] = acc[i][j] + bias;
        }
    __syncthreads();

    // 64 rows x 8 heads x 2 queues = 1024 tasks; 4 per thread
    for (int t = tid; t < OBM * NH * NQUEUE; t += 256) {
        const int lr = t >> 4;
        const int h = (t >> 1) & 7;
        const int queue = t & 1;
        const int gm = bm + lr;
        const int b = gm / NQ, q = gm - (gm / NQ) * NQ;

        const float* attn = &u.res[lr][128 + h * 8 + queue * 4];
        float l0 = attn[0], l1 = attn[1], l2 = attn[2], l3 = attn[3];
        float mx = fmaxf(fmaxf(l0, l1), fmaxf(l2, l3));
        float e0 = __expf(l0 - mx), e1 = __expf(l1 - mx);
        float e2 = __expf(l2 - mx), e3 = __expf(l3 - mx);
        float inv = 1.0f / (e0 + e1 + e2 + e3);
        float w[4] = {e0 * inv, e1 * inv, e2 * inv, e3 * inv};

        const int bq = b * 2 + queue;
        const float rx = ldin(refpts, ((size_t)bq * NQ + q) * 2 + 0, isf);
        const float ry = ldin(refpts, ((size_t)bq * NQ + q) * 2 + 1, isf);

        const float* od = &u.res[lr][h * 16 + queue * 8];
        float4* sp = samp + (((size_t)bq * NQ + q) * NH + h) * NP;
#pragma unroll
        for (int p = 0; p < NP; ++p) {
            float x = rx * (float)GW + od[p * 2 + 0] - 0.5f;
            float y = ry * (float)GH + od[p * 2 + 1] - 0.5f;
            sp[p] = make_float4(x, y, w[p], 0.0f);
        }
    }
}

// ---------------------------------------------------------------------------
// sample: per block = (b,q); thread = (h = tid>>5, d = tid&31)
// sampled[b][q][h*32+d] = 0.5 * sum_queue sum_p w_p * bilinear(v[bq])[h][d]
// v stored bf16 [BS*2, 6400, 256]; output bf16.
// ---------------------------------------------------------------------------
__global__ __launch_bounds__(256) void sample_k(
    const bf16* __restrict__ v, const float4* __restrict__ samp,
    bf16* __restrict__ sampled)
{
    const int blk = blockIdx.x;        // b*NQ + q
    const int b = blk / NQ;
    const int q = blk - b * NQ;
    const int tid = threadIdx.x;
    const int h = tid >> 5;
    const int d = tid & 31;

    float acc = 0.0f;
#pragma unroll
    for (int queue = 0; queue < NQUEUE; ++queue) {
        const int bq = b * 2 + queue;
        const bf16* vb = v + (size_t)bq * NQ * DIMS;
        const float4* sp = samp + (((size_t)bq * NQ + q) * NH + h) * NP;
#pragma unroll
        for (int p = 0; p < NP; ++p) {
            float4 s = sp[p];
            const float x = s.x, y = s.y, w = s.z;
            const float x0f = floorf(x), y0f = floorf(y);
            const float dx = x - x0f, dy = y - y0f;
            const int x0 = (int)x0f, y0 = (int)y0f;
            const float w00 = (1.0f - dx) * (1.0f - dy);
            const float w10 = dx * (1.0f - dy);
            const float w01 = (1.0f - dx) * dy;
            const float w11 = dx * dy;
            if ((unsigned)x0 < (unsigned)GW && (unsigned)y0 < (unsigned)GH)
                acc += w * w00 * b2f(vb[((size_t)(y0 * GW + x0) * NH + h) * 32 + d]);
            if ((unsigned)(x0 + 1) < (unsigned)GW && (unsigned)y0 < (unsigned)GH)
                acc += w * w10 * b2f(vb[((size_t)(y0 * GW + x0 + 1) * NH + h) * 32 + d]);
            if ((unsigned)x0 < (unsigned)GW && (unsigned)(y0 + 1) < (unsigned)GH)
                acc += w * w01 * b2f(vb[((size_t)((y0 + 1) * GW + x0) * NH + h) * 32 + d]);
            if ((unsigned)(x0 + 1) < (unsigned)GW && (unsigned)(y0 + 1) < (unsigned)GH)
                acc += w * w11 * b2f(vb[((size_t)((y0 + 1) * GW + x0 + 1) * NH + h) * 32 + d]);
        }
    }
    sampled[(size_t)blk * DIMS + tid] = f2b(0.5f * acc);
}

// ---------------------------------------------------------------------------
extern "C" void kernel_launch(void* const* d_in, const int* in_sizes, int n_in,
                              void* d_out, int out_size, void* d_ws, size_t ws_size,
                              hipStream_t stream)
{
    const void* query  = d_in[0];   // [4,6400,256]
    const void* voxbev = d_in[1];   // [4,6400,256]
    const void* refpts = d_in[2];   // [8,6400,1,2]
    // d_in[3] spatial_shapes=[[80,80]], d_in[4] level_start_index=[0]: hardcoded
    const void* Wv     = d_in[5];   // [256,256]
    const void* bv     = d_in[6];   // [256]
    const void* Woff   = d_in[7];   // [512,128]
    const void* boff   = d_in[8];   // [128]
    const void* Wattn  = d_in[9];   // [512,64]
    const void* battn  = d_in[10];  // [64]
    const void* Wo     = d_in[11];  // [256,256]
    const void* bo     = d_in[12];  // [256]

    // workspace layout (62.5 MiB total)
    char* wsb = (char*)d_ws;
    int*    flag    = (int*)wsb;                          // 16 B reserved
    bf16*   v_ws    = (bf16*)(wsb + 16);                  // 8*6400*256 bf16 = 26,214,400 B
    float4* samp    = (float4*)(wsb + 16 + 26214400);     // 8*6400*8*4 f4   = 26,214,400 B
    bf16*   sampled = (bf16*)(wsb + 16 + 2 * 26214400);   // 4*6400*256 bf16 = 13,107,200 B

    // 0. detect input dtype (f32 vs bf16)
    detect_k<<<1, 256, 0, stream>>>((const unsigned short*)query, flag);

    // 1. value projection: v = interleave(query,voxbev) @ Wv + bv  [51200,256] bf16
    gemm_k<0, 1><<<dim3(DIMS / BN, (NQUEUE * BS * NQ) / BM), 256, 0, stream>>>(
        nullptr, Wv, bv, (void*)v_ws, NQUEUE * BS * NQ, DIMS, DIMS,
        query, voxbev, nullptr, flag);

    // 2+3+4. fused offsets + attn logits + softmax + sampling coords
    offattn_k<<<(BS * NQ) / OBM, 256, 0, stream>>>(
        query, voxbev, refpts, Woff, boff, Wattn, battn, flag, samp);

    // 5. deformable bilinear sampling + queue mean  [25600,256] bf16
    sample_k<<<BS * NQ, 256, 0, stream>>>(v_ws, samp, sampled);

    // 6. output projection + residual: out = sampled @ Wo + bo + query
    gemm_k<2, 2><<<dim3(DIMS / BN, (BS * NQ) / BM), 256, 0, stream>>>(
        sampled, Wo, bo, d_out, BS * NQ, DIMS, DIMS,
        query, voxbev, query, flag);
}

// Round 3
// 286.449 us; speedup vs baseline: 2.4774x; 2.4774x over previous
//
#include <hip/hip_runtime.h>
#include <hip/hip_bf16.h>

// Problem constants (fixed by setup_inputs)
#define BS   4
#define NQ   6400
#define DIMS 256
#define NH   8
#define NP   4
#define GW   80
#define GH   80

typedef __hip_bfloat16 bf16;
typedef __attribute__((ext_vector_type(8))) short short8;   // 8 bf16 = 4 VGPRs (MFMA A/B frag)
typedef __attribute__((ext_vector_type(4))) float floatx4;  // MFMA C/D frag

union bfu { bf16 h; unsigned short s; };

__device__ __forceinline__ unsigned short f2bs(float x) { bfu u; u.h = __float2bfloat16(x); return u.s; }
__device__ __forceinline__ float bs2f(unsigned short s) { return __uint_as_float(((unsigned)s) << 16); }
// Flag-predicated input load: inputs are either f32 or bf16 (runtime-detected).
__device__ __forceinline__ float ldin(const void* p, size_t i, int isf) {
    return isf ? ((const float*)p)[i] : bs2f(((const unsigned short*)p)[i]);
}

// ---------------------------------------------------------------------------
// dtype detector: f32-packed data read as bf16 shows impossible exponents.
// flag=1 -> inputs are f32; flag=0 -> bf16.
// ---------------------------------------------------------------------------
__global__ void detect_k(const unsigned short* __restrict__ q, int* flag) {
    __shared__ int s;
    if (threadIdx.x == 0) s = 0;
    __syncthreads();
    int bad = 0;
    for (int j = 0; j < 16; ++j) {
        unsigned short v = q[threadIdx.x * 16 + j];
        int e = (v >> 7) & 0xFF;
        if (e > 160) bad = 1;   // |x| >= 2^33: impossible for real bf16 data
    }
    if (bad) atomicOr(&s, 1);
    __syncthreads();
    if (threadIdx.x == 0) *flag = s;
}

// ---------------------------------------------------------------------------
// Weight prep: transpose+convert weights to bf16 B^T[n][k]; biases to f32.
// WoaT combines [Woff | Wattn] columns (192 x 512).
// ---------------------------------------------------------------------------
__global__ void wprep_k(
    const void* __restrict__ Wv, const void* __restrict__ bv,
    const void* __restrict__ Woff, const void* __restrict__ boff,
    const void* __restrict__ Wattn, const void* __restrict__ battn,
    const void* __restrict__ Wo, const void* __restrict__ bo,
    const int* __restrict__ flagp,
    unsigned short* __restrict__ WvT, unsigned short* __restrict__ WoaT,
    unsigned short* __restrict__ WoT,
    float* __restrict__ biasv, float* __restrict__ biasoa, float* __restrict__ biaso)
{
    const int isf = *flagp;
    const int i = blockIdx.x * 256 + threadIdx.x;
    const int n1 = 256 * 256, n2 = n1 + 192 * 512, n3 = n2 + 256 * 256;
    const int n4 = n3 + 256, n5 = n4 + 192, n6 = n5 + 256;
    if (i < n1) {
        int n = i >> 8, k = i & 255;
        WvT[i] = f2bs(ldin(Wv, (size_t)k * 256 + n, isf));
    } else if (i < n2) {
        int j = i - n1, n = j >> 9, k = j & 511;
        float v = (n < 128) ? ldin(Woff, (size_t)k * 128 + n, isf)
                            : ldin(Wattn, (size_t)k * 64 + (n - 128), isf);
        WoaT[j] = f2bs(v);
    } else if (i < n3) {
        int j = i - n2, n = j >> 8, k = j & 255;
        WoT[j] = f2bs(ldin(Wo, (size_t)k * 256 + n, isf));
    } else if (i < n4) {
        biasv[i - n3] = ldin(bv, i - n3, isf);
    } else if (i < n5) {
        int j = i - n4;
        biasoa[j] = (j < 128) ? ldin(boff, j, isf) : ldin(battn, j - 128, isf);
    } else if (i < n6) {
        biaso[i - n5] = ldin(bo, i - n5, isf);
    }
}

// ---------------------------------------------------------------------------
// Load 16 consecutive input elements -> bf16 bits into LDS.
// ---------------------------------------------------------------------------
__device__ __forceinline__ void load16(short* dst, const void* src, size_t off, int isf) {
    if (isf) {
        const float4* p = (const float4*)((const float*)src + off);
#pragma unroll
        for (int c = 0; c < 4; ++c) {
            float4 v = p[c];
            dst[c * 4 + 0] = (short)f2bs(v.x);
            dst[c * 4 + 1] = (short)f2bs(v.y);
            dst[c * 4 + 2] = (short)f2bs(v.z);
            dst[c * 4 + 3] = (short)f2bs(v.w);
        }
    } else {
        const short8* p = (const short8*)((const unsigned short*)src + off);
        *(short8*)dst       = p[0];
        *(short8*)(dst + 8) = p[1];
    }
}

// ---------------------------------------------------------------------------
// MFMA GEMM: C[M,N] = gatherA[M,K] @ B + bias. B supplied transposed bf16
// BT[n][k]. Block tile 128(M) x 64(N), BK=32, 4 waves each 64x32 (4x2 grid
// of 16x16x32 MFMA). LDS stride 40 shorts (80 B) -> 2-way-only conflicts.
// A gather: A_VAL   row m -> interleaved value row (bq=m/NQ)
//           A_QCAT  row m -> [value row b | query row], K=512
//           A_PLAIN plain bf16-bits pointer, stride K
// Out:      O_BF16 bf16 bits; O_F32 f32; O_FINAL +addend, dtype per flag
// ---------------------------------------------------------------------------
enum { A_VAL = 0, A_QCAT = 1, A_PLAIN = 2 };
enum { O_BF16 = 0, O_F32 = 1, O_FINAL = 2 };

template <int AMODE, int OMODE>
__global__ __launch_bounds__(256) void mgemm_k(
    const unsigned short* __restrict__ Apl, const unsigned short* __restrict__ BT,
    const float* __restrict__ biasf, void* __restrict__ C,
    const void* __restrict__ query, const void* __restrict__ voxbev,
    const void* __restrict__ addend, const int* __restrict__ flagp,
    int N, int K)
{
    const int isf = *flagp;
    __shared__ short As[128][40];
    __shared__ short Bs[64][40];

    const int tid = threadIdx.x;
    const int bm = blockIdx.y * 128;
    const int bn = blockIdx.x * 64;

    // A staging: thread -> row tid>>1, k-half (tid&1)*16
    const int ar = tid >> 1, ah = (tid & 1) * 16;
    const int m = bm + ar;
    const void* slo = nullptr; const void* shi = nullptr;
    size_t blo = 0, bhi = 0;
    if (AMODE == A_VAL) {
        const int bq = m / NQ, q = m - bq * NQ;
        slo = (bq & 1) ? voxbev : query;
        blo = (size_t)((bq >> 1) * NQ + q) * DIMS;
    } else if (AMODE == A_QCAT) {
        const int b = m / NQ, q = m - b * NQ;
        slo = (b & 1) ? voxbev : query;
        blo = (size_t)((b >> 1) * NQ + q) * DIMS;
        shi = query; bhi = (size_t)(b * NQ + q) * DIMS;
    }
    // B staging: thread -> n-row tid>>2, k-chunk (tid&3)*8
    const int bnr = tid >> 2, bc = (tid & 3) * 8;
    const unsigned short* btrow = BT + (size_t)(bn + bnr) * K + bc;

    const int lane = tid & 63, wv = tid >> 6;
    const int wm = (wv & 1) * 64, wn = (wv >> 1) * 32;
    const int fr = lane & 15, fq = (lane >> 4) * 8;

    floatx4 acc[4][2] = {};

    for (int k0 = 0; k0 < K; k0 += 32) {
        const int s = k0 + ah;
        if (AMODE == A_PLAIN) {
            const short8* p = (const short8*)(Apl + (size_t)m * K + s);
            *(short8*)&As[ar][ah]     = p[0];
            *(short8*)&As[ar][ah + 8] = p[1];
        } else if (AMODE == A_VAL) {
            load16(&As[ar][ah], slo, blo + s, isf);
        } else {
            if (s < DIMS) load16(&As[ar][ah], slo, blo + s, isf);
            else          load16(&As[ar][ah], shi, bhi + (s - DIMS), isf);
        }
        *(short8*)&Bs[bnr][bc] = *(const short8*)(btrow + k0);
        __syncthreads();

        short8 af[4], bf[2];
#pragma unroll
        for (int mt = 0; mt < 4; ++mt)
            af[mt] = *(const short8*)&As[wm + mt * 16 + fr][fq];
#pragma unroll
        for (int nt = 0; nt < 2; ++nt)
            bf[nt] = *(const short8*)&Bs[wn + nt * 16 + fr][fq];
#pragma unroll
        for (int mt = 0; mt < 4; ++mt)
#pragma unroll
            for (int nt = 0; nt < 2; ++nt)
                acc[mt][nt] = __builtin_amdgcn_mfma_f32_16x16x32_bf16(
                    af[mt], bf[nt], acc[mt][nt], 0, 0, 0);
        __syncthreads();
    }

    // Epilogue. C/D layout: col=lane&15, row=(lane>>4)*4+reg (m89-verified).
    const int col = lane & 15, rq = (lane >> 4) * 4;
#pragma unroll
    for (int mt = 0; mt < 4; ++mt)
#pragma unroll
        for (int nt = 0; nt < 2; ++nt)
#pragma unroll
            for (int r = 0; r < 4; ++r) {
                const int grow = bm + wm + mt * 16 + rq + r;
                const int gcol = bn + wn + nt * 16 + col;
                float val = acc[mt][nt][r] + biasf[gcol];
                if (OMODE == O_BF16) {
                    ((unsigned short*)C)[(size_t)grow * N + gcol] = f2bs(val);
                } else if (OMODE == O_F32) {
                    ((float*)C)[(size_t)grow * N + gcol] = val;
                } else {
                    val += ldin(addend, (size_t)grow * N + gcol, isf);
                    if (isf) ((float*)C)[(size_t)grow * N + gcol] = val;
                    else     ((unsigned short*)C)[(size_t)grow * N + gcol] = f2bs(val);
                }
            }
}

// ---------------------------------------------------------------------------
// Fused softmax + coords + bilinear sampling + queue mean.
// Block = 2 queries. Phase 1 (threads 0..31): per (lq,queue,h) softmax over
// 4 logits + pixel coords -> LDS (0.5 queue-mean folded into weights).
// Phase 2: thread = (lq, h, d-pair); gathers bf16x2, accumulates f32.
// ---------------------------------------------------------------------------
__global__ __launch_bounds__(256) void sample_k(
    const unsigned short* __restrict__ v,      // [BS*2, NQ, 256] bf16 bits
    const float* __restrict__ offraw,          // [BS*NQ, 192] f32
    const void* __restrict__ refpts,           // [BS*2, NQ, 1, 2] input dtype
    const int* __restrict__ flagp,
    unsigned short* __restrict__ sampled)      // [BS*NQ, 256] bf16 bits
{
    const int isf = *flagp;
    __shared__ float sx[2][2][8][4], sy[2][2][8][4], sw[2][2][8][4];
    const int tid = threadIdx.x;
    const int gq0 = blockIdx.x * 2;

    if (tid < 32) {
        const int lq = tid >> 4, queue = (tid >> 3) & 1, h = tid & 7;
        const int gq = gq0 + lq;
        const int b = gq / NQ, q = gq - b * NQ;
        const float* row = offraw + (size_t)gq * 192;
        const float* al = row + 128 + h * 8 + queue * 4;
        float l0 = al[0], l1 = al[1], l2 = al[2], l3 = al[3];
        float mx = fmaxf(fmaxf(l0, l1), fmaxf(l2, l3));
        float e0 = __expf(l0 - mx), e1 = __expf(l1 - mx);
        float e2 = __expf(l2 - mx), e3 = __expf(l3 - mx);
        float inv = 0.5f / (e0 + e1 + e2 + e3);   // fold queue-mean 0.5
        const int bq = b * 2 + queue;
        const float rx = ldin(refpts, ((size_t)bq * NQ + q) * 2 + 0, isf);
        const float ry = ldin(refpts, ((size_t)bq * NQ + q) * 2 + 1, isf);
        const float* od = row + h * 16 + queue * 8;
        float ww[4] = { e0 * inv, e1 * inv, e2 * inv, e3 * inv };
#pragma unroll
        for (int p = 0; p < NP; ++p) {
            sx[lq][queue][h][p] = rx * (float)GW + od[p * 2 + 0] - 0.5f;
            sy[lq][queue][h][p] = ry * (float)GH + od[p * 2 + 1] - 0.5f;
            sw[lq][queue][h][p] = ww[p];
        }
    }
    __syncthreads();

    const int lq = tid >> 7, h = (tid >> 4) & 7, d2 = tid & 15;
    const int gq = gq0 + lq;
    const int b = gq / NQ;
    const int doff = h * 32 + d2 * 2;
    float a0 = 0.0f, a1 = 0.0f;
#pragma unroll
    for (int queue = 0; queue < 2; ++queue) {
        const unsigned short* vb = v + (size_t)(b * 2 + queue) * NQ * DIMS;
#pragma unroll
        for (int p = 0; p < NP; ++p) {
            const float x = sx[lq][queue][h][p];
            const float y = sy[lq][queue][h][p];
            const float w = sw[lq][queue][h][p];
            const float x0f = floorf(x), y0f = floorf(y);
            const float dx = x - x0f, dy = y - y0f;
            const int x0 = (int)x0f, y0 = (int)y0f;
            const float c00 = w * (1.0f - dx) * (1.0f - dy);
            const float c10 = w * dx * (1.0f - dy);
            const float c01 = w * (1.0f - dx) * dy;
            const float c11 = w * dx * dy;
#define CORNER(xi, yi, cw)                                                      \
            if ((unsigned)(xi) < (unsigned)GW && (unsigned)(yi) < (unsigned)GH) { \
                unsigned u = *(const unsigned*)&vb[(size_t)((yi) * GW + (xi)) * DIMS + doff]; \
                a0 += (cw) * bs2f((unsigned short)u);                            \
                a1 += (cw) * bs2f((unsigned short)(u >> 16));                    \
            }
            CORNER(x0,     y0,     c00)
            CORNER(x0 + 1, y0,     c10)
            CORNER(x0,     y0 + 1, c01)
            CORNER(x0 + 1, y0 + 1, c11)
#undef CORNER
        }
    }
    const size_t o = (size_t)gq * DIMS + doff;
    *(unsigned*)&sampled[o] = ((unsigned)f2bs(a1) << 16) | (unsigned)f2bs(a0);
}

// ---------------------------------------------------------------------------
extern "C" void kernel_launch(void* const* d_in, const int* in_sizes, int n_in,
                              void* d_out, int out_size, void* d_ws, size_t ws_size,
                              hipStream_t stream)
{
    const void* query  = d_in[0];   // [4,6400,256]
    const void* voxbev = d_in[1];   // [4,6400,256]
    const void* refpts = d_in[2];   // [8,6400,1,2]
    // d_in[3] spatial_shapes=[[80,80]], d_in[4] level_start_index=[0]: hardcoded
    const void* Wv     = d_in[5];
    const void* bv     = d_in[6];
    const void* Woff   = d_in[7];
    const void* boff   = d_in[8];
    const void* Wattn  = d_in[9];
    const void* battn  = d_in[10];
    const void* Wo     = d_in[11];
    const void* bo     = d_in[12];

    // workspace layout (~59.3 MB, under the proven 62.5 MB budget)
    char* p = (char*)d_ws;
    int* flag = (int*)p;                        p += 256;
    unsigned short* WvT  = (unsigned short*)p;  p += 256 * 256 * 2;
    unsigned short* WoaT = (unsigned short*)p;  p += 192 * 512 * 2;
    unsigned short* WoT  = (unsigned short*)p;  p += 256 * 256 * 2;
    float* biasv  = (float*)p;                  p += 256 * 4;
    float* biasoa = (float*)p;                  p += 192 * 4;
    float* biaso  = (float*)p;                  p += 256 * 4;
    unsigned short* v_ws = (unsigned short*)p;  p += (size_t)51200 * 256 * 2;  // 26.2 MB
    float* offraw = (float*)p;                  p += (size_t)25600 * 192 * 4;  // 19.7 MB
    unsigned short* sampled = (unsigned short*)p;  // 13.1 MB

    // 0. dtype detect + weight transpose/convert
    detect_k<<<1, 256, 0, stream>>>((const unsigned short*)query, flag);
    wprep_k<<<899, 256, 0, stream>>>(Wv, bv, Woff, boff, Wattn, battn, Wo, bo,
                                     flag, WvT, WoaT, WoT, biasv, biasoa, biaso);

    // 1. value projection: v = interleave(query,voxbev) @ Wv + bv  [51200,256] bf16
    mgemm_k<A_VAL, O_BF16><<<dim3(4, 400), 256, 0, stream>>>(
        nullptr, WvT, biasv, (void*)v_ws, query, voxbev, nullptr, flag, 256, 256);

    // 2. offsets+attn logits: offraw = qcat @ [Woff|Wattn] + bias  [25600,192] f32
    mgemm_k<A_QCAT, O_F32><<<dim3(3, 200), 256, 0, stream>>>(
        nullptr, WoaT, biasoa, (void*)offraw, query, voxbev, nullptr, flag, 192, 512);

    // 3. fused softmax + coords + bilinear sampling + queue mean  [25600,256] bf16
    sample_k<<<12800, 256, 0, stream>>>(v_ws, offraw, refpts, flag, sampled);

    // 4. output projection + residual: out = sampled @ Wo + bo + query
    mgemm_k<A_PLAIN, O_FINAL><<<dim3(4, 200), 256, 0, stream>>>(
        sampled, WoT, biaso, d_out, query, voxbev, query, flag, 256, 256);
}

// Round 4
// 243.990 us; speedup vs baseline: 2.9085x; 1.1740x over previous
//
#include <hip/hip_runtime.h>
#include <hip/hip_bf16.h>

// Problem constants (fixed by setup_inputs)
#define BS   4
#define NQ   6400
#define DIMS 256
#define NH   8
#define NP   4
#define GW   80
#define GH   80

typedef __hip_bfloat16 bf16;
typedef __attribute__((ext_vector_type(8))) short short8;   // 8 bf16 (MFMA A/B frag)
typedef __attribute__((ext_vector_type(4))) float floatx4;  // MFMA C/D frag

union bfu { bf16 h; unsigned short s; };

__device__ __forceinline__ unsigned short f2bs(float x) { bfu u; u.h = __float2bfloat16(x); return u.s; }
__device__ __forceinline__ float bs2f(unsigned short s) { return __uint_as_float(((unsigned)s) << 16); }
__device__ __forceinline__ float ldin(const void* p, size_t i, int isf) {
    return isf ? ((const float*)p)[i] : bs2f(((const unsigned short*)p)[i]);
}

// ---------------------------------------------------------------------------
// dtype detector: f32-packed data read as bf16 shows impossible exponents.
// flag=1 -> inputs are f32; flag=0 -> bf16.
// ---------------------------------------------------------------------------
__global__ void detect_k(const unsigned short* __restrict__ q, int* flag) {
    __shared__ int s;
    if (threadIdx.x == 0) s = 0;
    __syncthreads();
    int bad = 0;
    for (int j = 0; j < 16; ++j) {
        unsigned short v = q[threadIdx.x * 16 + j];
        int e = (v >> 7) & 0xFF;
        if (e > 160) bad = 1;
    }
    if (bad) atomicOr(&s, 1);
    __syncthreads();
    if (threadIdx.x == 0) *flag = s;
}

// ---------------------------------------------------------------------------
// Weight prep: transpose+convert weights to bf16 B^T[n][k]; biases to f32.
// ---------------------------------------------------------------------------
__global__ void wprep_k(
    const void* __restrict__ Wv, const void* __restrict__ bv,
    const void* __restrict__ Woff, const void* __restrict__ boff,
    const void* __restrict__ Wattn, const void* __restrict__ battn,
    const void* __restrict__ Wo, const void* __restrict__ bo,
    const int* __restrict__ flagp,
    unsigned short* __restrict__ WvT, unsigned short* __restrict__ WoaT,
    unsigned short* __restrict__ WoT,
    float* __restrict__ biasv, float* __restrict__ biasoa, float* __restrict__ biaso)
{
    const int isf = *flagp;
    const int i = blockIdx.x * 256 + threadIdx.x;
    const int n1 = 256 * 256, n2 = n1 + 192 * 512, n3 = n2 + 256 * 256;
    const int n4 = n3 + 256, n5 = n4 + 192, n6 = n5 + 256;
    if (i < n1) {
        int n = i >> 8, k = i & 255;
        WvT[i] = f2bs(ldin(Wv, (size_t)k * 256 + n, isf));
    } else if (i < n2) {
        int j = i - n1, n = j >> 9, k = j & 511;
        float v = (n < 128) ? ldin(Woff, (size_t)k * 128 + n, isf)
                            : ldin(Wattn, (size_t)k * 64 + (n - 128), isf);
        WoaT[j] = f2bs(v);
    } else if (i < n3) {
        int j = i - n2, n = j >> 8, k = j & 255;
        WoT[j] = f2bs(ldin(Wo, (size_t)k * 256 + n, isf));
    } else if (i < n4) {
        biasv[i - n3] = ldin(bv, i - n3, isf);
    } else if (i < n5) {
        int j = i - n4;
        biasoa[j] = (j < 128) ? ldin(boff, j, isf) : ldin(battn, j - 128, isf);
    } else if (i < n6) {
        biaso[i - n5] = ldin(bo, i - n5, isf);
    }
}

// Load 16 consecutive input elements -> bf16 bits into LDS.
__device__ __forceinline__ void load16(short* dst, const void* src, size_t off, int isf) {
    if (isf) {
        const float4* p = (const float4*)((const float*)src + off);
#pragma unroll
        for (int c = 0; c < 4; ++c) {
            float4 v = p[c];
            dst[c * 4 + 0] = (short)f2bs(v.x);
            dst[c * 4 + 1] = (short)f2bs(v.y);
            dst[c * 4 + 2] = (short)f2bs(v.z);
            dst[c * 4 + 3] = (short)f2bs(v.w);
        }
    } else {
        const short8* p = (const short8*)((const unsigned short*)src + off);
        *(short8*)dst       = p[0];
        *(short8*)(dst + 8) = p[1];
    }
}

// ---------------------------------------------------------------------------
// MFMA GEMM: C[M,N] = gatherA[M,K] @ B + bias. B pre-transposed bf16 BT[n][k].
// Block tile 128(M) x BN, BK=32, 4 waves as 2x2, each wave 64 x BN/2
// (4 x BN/32 grid of 16x16x32 MFMA -> 16 MFMA/barrier for BN=128).
// LDS stride 40 shorts (80 B) -> only 2-way conflicts (free, m136).
// ---------------------------------------------------------------------------
enum { A_VAL = 0, A_QCAT = 1, A_PLAIN = 2 };
enum { O_BF16 = 0, O_F32 = 1, O_FINAL = 2 };

template <int AMODE, int OMODE, int BN>
__global__ __launch_bounds__(256) void mgemm_k(
    const unsigned short* __restrict__ Apl, const unsigned short* __restrict__ BT,
    const float* __restrict__ biasf, void* __restrict__ C,
    const void* __restrict__ query, const void* __restrict__ voxbev,
    const void* __restrict__ addend, const int* __restrict__ flagp,
    int N, int K)
{
    const int isf = *flagp;
    __shared__ short As[128][40];
    __shared__ short Bs[BN][40];

    const int tid = threadIdx.x;
    const int bm = blockIdx.y * 128;
    const int bn = blockIdx.x * BN;

    // A staging: thread -> row tid>>1, k-half (tid&1)*16
    const int ar = tid >> 1, ah = (tid & 1) * 16;
    const int m = bm + ar;
    const void* slo = nullptr; const void* shi = nullptr;
    size_t blo = 0, bhi = 0;
    if (AMODE == A_VAL) {
        const int bq = m / NQ, q = m - bq * NQ;
        slo = (bq & 1) ? voxbev : query;
        blo = (size_t)((bq >> 1) * NQ + q) * DIMS;
    } else if (AMODE == A_QCAT) {
        const int b = m / NQ, q = m - b * NQ;
        slo = (b & 1) ? voxbev : query;
        blo = (size_t)((b >> 1) * NQ + q) * DIMS;
        shi = query; bhi = (size_t)(b * NQ + q) * DIMS;
    }
    // B staging: thread -> n-row tid>>1, k-half (tid&1)*16 (tid < 2*BN)
    const int bnr = tid >> 1, bh = (tid & 1) * 16;
    const unsigned short* btrow = BT + (size_t)(bn + bnr) * K + bh;

    const int lane = tid & 63, wv = tid >> 6;
    const int wm = (wv & 1) * 64, wn = (wv >> 1) * (BN / 2);
    const int fr = lane & 15, fq = (lane >> 4) * 8;
    const int NT = BN / 32;

    floatx4 acc[4][BN / 32] = {};

    for (int k0 = 0; k0 < K; k0 += 32) {
        const int s = k0 + ah;
        if (AMODE == A_PLAIN) {
            const short8* p = (const short8*)(Apl + (size_t)m * K + s);
            *(short8*)&As[ar][ah]     = p[0];
            *(short8*)&As[ar][ah + 8] = p[1];
        } else if (AMODE == A_VAL) {
            load16(&As[ar][ah], slo, blo + s, isf);
        } else {
            if (s < DIMS) load16(&As[ar][ah], slo, blo + s, isf);
            else          load16(&As[ar][ah], shi, bhi + (s - DIMS), isf);
        }
        if (BN == 128 || tid < 2 * BN) {
            const short8* p = (const short8*)(btrow + k0);
            *(short8*)&Bs[bnr][bh]     = p[0];
            *(short8*)&Bs[bnr][bh + 8] = p[1];
        }
        __syncthreads();

        short8 af[4], bfr[BN / 32];
#pragma unroll
        for (int mt = 0; mt < 4; ++mt)
            af[mt] = *(const short8*)&As[wm + mt * 16 + fr][fq];
#pragma unroll
        for (int nt = 0; nt < NT; ++nt)
            bfr[nt] = *(const short8*)&Bs[wn + nt * 16 + fr][fq];
#pragma unroll
        for (int mt = 0; mt < 4; ++mt)
#pragma unroll
            for (int nt = 0; nt < NT; ++nt)
                acc[mt][nt] = __builtin_amdgcn_mfma_f32_16x16x32_bf16(
                    af[mt], bfr[nt], acc[mt][nt], 0, 0, 0);
        __syncthreads();
    }

    // Epilogue. C/D layout: col=lane&15, row=(lane>>4)*4+reg (m89-verified).
    const int col = lane & 15, rq = (lane >> 4) * 4;
#pragma unroll
    for (int mt = 0; mt < 4; ++mt)
#pragma unroll
        for (int nt = 0; nt < NT; ++nt)
#pragma unroll
            for (int r = 0; r < 4; ++r) {
                const int grow = bm + wm + mt * 16 + rq + r;
                const int gcol = bn + wn + nt * 16 + col;
                float val = acc[mt][nt][r] + biasf[gcol];
                if (OMODE == O_BF16) {
                    ((unsigned short*)C)[(size_t)grow * N + gcol] = f2bs(val);
                } else if (OMODE == O_F32) {
                    ((float*)C)[(size_t)grow * N + gcol] = val;
                } else {
                    val += ldin(addend, (size_t)grow * N + gcol, isf);
                    if (isf) ((float*)C)[(size_t)grow * N + gcol] = val;
                    else     ((unsigned short*)C)[(size_t)grow * N + gcol] = f2bs(val);
                }
            }
}

// ---------------------------------------------------------------------------
// Fused softmax + coords + bilinear sampling + queue mean.
// Block = 4 queries of ONE batch b; XCD-swizzled: blockIdx%8 -> {2b,2b+1}
// so each XCD touches only batch b's two images (6.4 MB) for L2 locality.
// Phase 1 (threads 0..63): per (lq,queue,h) softmax + pixel coords -> LDS.
// Phase 2: wave = 1 query; thread = (h, d4); dwordx2 gathers (4 dims).
// ---------------------------------------------------------------------------
__global__ __launch_bounds__(256) void sample_k(
    const unsigned short* __restrict__ v,      // [BS*2, NQ, 256] bf16 bits
    const float* __restrict__ offraw,          // [BS*NQ, 192] f32
    const void* __restrict__ refpts,           // [BS*2, NQ, 1, 2] input dtype
    const int* __restrict__ flagp,
    unsigned short* __restrict__ sampled)      // [BS*NQ, 256] bf16 bits
{
    const int isf = *flagp;
    __shared__ float sx[4][2][8][4], sy[4][2][8][4], sw[4][2][8][4];
    const int tid = threadIdx.x;

    const int j = blockIdx.x;
    const int slot = j & 7;
    const int b = slot >> 1;
    const int idx = ((j >> 3) << 1) + (slot & 1);   // 0..1599
    const int q0 = idx * 4;

    if (tid < 64) {
        const int lq = tid >> 4, queue = (tid >> 3) & 1, h = tid & 7;
        const int q = q0 + lq;
        const int gq = b * NQ + q;
        const float* row = offraw + (size_t)gq * 192;
        const float* al = row + 128 + h * 8 + queue * 4;
        float l0 = al[0], l1 = al[1], l2 = al[2], l3 = al[3];
        float mx = fmaxf(fmaxf(l0, l1), fmaxf(l2, l3));
        float e0 = __expf(l0 - mx), e1 = __expf(l1 - mx);
        float e2 = __expf(l2 - mx), e3 = __expf(l3 - mx);
        float inv = 0.5f / (e0 + e1 + e2 + e3);   // fold queue-mean 0.5
        const int bq = b * 2 + queue;
        const float rx = ldin(refpts, ((size_t)bq * NQ + q) * 2 + 0, isf);
        const float ry = ldin(refpts, ((size_t)bq * NQ + q) * 2 + 1, isf);
        const float* od = row + h * 16 + queue * 8;
        float ww[4] = { e0 * inv, e1 * inv, e2 * inv, e3 * inv };
#pragma unroll
        for (int p = 0; p < NP; ++p) {
            sx[lq][queue][h][p] = rx * (float)GW + od[p * 2 + 0] - 0.5f;
            sy[lq][queue][h][p] = ry * (float)GH + od[p * 2 + 1] - 0.5f;
            sw[lq][queue][h][p] = ww[p];
        }
    }
    __syncthreads();

    const int lq = tid >> 6, h = (tid >> 3) & 7, d4 = tid & 7;
    const int gq = b * NQ + q0 + lq;
    const int doff = h * 32 + d4 * 4;
    float a0 = 0.f, a1 = 0.f, a2 = 0.f, a3 = 0.f;
#pragma unroll
    for (int queue = 0; queue < 2; ++queue) {
        const unsigned short* vb = v + (size_t)(b * 2 + queue) * NQ * DIMS;
#pragma unroll
        for (int p = 0; p < NP; ++p) {
            const float x = sx[lq][queue][h][p];
            const float y = sy[lq][queue][h][p];
            const float w = sw[lq][queue][h][p];
            const float x0f = floorf(x), y0f = floorf(y);
            const float dx = x - x0f, dy = y - y0f;
            const int x0 = (int)x0f, y0 = (int)y0f;
            const float c00 = w * (1.0f - dx) * (1.0f - dy);
            const float c10 = w * dx * (1.0f - dy);
            const float c01 = w * (1.0f - dx) * dy;
            const float c11 = w * dx * dy;
#define CORNER(xi, yi, cw)                                                        \
            if ((unsigned)(xi) < (unsigned)GW && (unsigned)(yi) < (unsigned)GH) { \
                const uint2 u = *(const uint2*)&vb[(size_t)((yi) * GW + (xi)) * DIMS + doff]; \
                a0 += (cw) * bs2f((unsigned short)u.x);                           \
                a1 += (cw) * bs2f((unsigned short)(u.x >> 16));                   \
                a2 += (cw) * bs2f((unsigned short)u.y);                           \
                a3 += (cw) * bs2f((unsigned short)(u.y >> 16));                   \
            }
            CORNER(x0,     y0,     c00)
            CORNER(x0 + 1, y0,     c10)
            CORNER(x0,     y0 + 1, c01)
            CORNER(x0 + 1, y0 + 1, c11)
#undef CORNER
        }
    }
    uint2 o;
    o.x = ((unsigned)f2bs(a1) << 16) | (unsigned)f2bs(a0);
    o.y = ((unsigned)f2bs(a3) << 16) | (unsigned)f2bs(a2);
    *(uint2*)&sampled[(size_t)gq * DIMS + doff] = o;
}

// ---------------------------------------------------------------------------
extern "C" void kernel_launch(void* const* d_in, const int* in_sizes, int n_in,
                              void* d_out, int out_size, void* d_ws, size_t ws_size,
                              hipStream_t stream)
{
    const void* query  = d_in[0];
    const void* voxbev = d_in[1];
    const void* refpts = d_in[2];
    // d_in[3] spatial_shapes=[[80,80]], d_in[4] level_start_index=[0]: hardcoded
    const void* Wv     = d_in[5];
    const void* bv     = d_in[6];
    const void* Woff   = d_in[7];
    const void* boff   = d_in[8];
    const void* Wattn  = d_in[9];
    const void* battn  = d_in[10];
    const void* Wo     = d_in[11];
    const void* bo     = d_in[12];

    // workspace layout (~59.5 MB, within proven budget)
    char* p = (char*)d_ws;
    int* flag = (int*)p;                        p += 256;
    unsigned short* WvT  = (unsigned short*)p;  p += 256 * 256 * 2;
    unsigned short* WoaT = (unsigned short*)p;  p += 192 * 512 * 2;
    unsigned short* WoT  = (unsigned short*)p;  p += 256 * 256 * 2;
    float* biasv  = (float*)p;                  p += 256 * 4;
    float* biasoa = (float*)p;                  p += 192 * 4;
    float* biaso  = (float*)p;                  p += 256 * 4;
    unsigned short* v_ws = (unsigned short*)p;  p += (size_t)51200 * 256 * 2;  // 26.2 MB
    float* offraw = (float*)p;                  p += (size_t)25600 * 192 * 4;  // 19.7 MB
    unsigned short* sampled = (unsigned short*)p;  // 13.1 MB

    // 0. dtype detect + weight transpose/convert
    detect_k<<<1, 256, 0, stream>>>((const unsigned short*)query, flag);
    wprep_k<<<899, 256, 0, stream>>>(Wv, bv, Woff, boff, Wattn, battn, Wo, bo,
                                     flag, WvT, WoaT, WoT, biasv, biasoa, biaso);

    // 1. value projection: v = interleave(query,voxbev) @ Wv + bv  [51200,256] bf16
    mgemm_k<A_VAL, O_BF16, 128><<<dim3(2, 400), 256, 0, stream>>>(
        nullptr, WvT, biasv, (void*)v_ws, query, voxbev, nullptr, flag, 256, 256);

    // 2. offsets+attn logits: offraw = qcat @ [Woff|Wattn] + bias  [25600,192] f32
    mgemm_k<A_QCAT, O_F32, 96><<<dim3(2, 200), 256, 0, stream>>>(
        nullptr, WoaT, biasoa, (void*)offraw, query, voxbev, nullptr, flag, 192, 512);

    // 3. fused softmax + coords + bilinear sampling + queue mean  [25600,256] bf16
    sample_k<<<6400, 256, 0, stream>>>(v_ws, offraw, refpts, flag, sampled);

    // 4. output projection + residual: out = sampled @ Wo + bo + query
    mgemm_k<A_PLAIN, O_FINAL, 128><<<dim3(2, 200), 256, 0, stream>>>(
        sampled, WoT, biaso, d_out, query, voxbev, query, flag, 256, 256);
}